// Round 1
// baseline (391.935 us; speedup 1.0000x reference)
//
#include <hip/hip_runtime.h>

// dijetReinforceLayer via MFMA, R3: direct-from-global fragment gather.
// out[n,o,s] = b[o] + sum_{c,j} W[o,c,j] * din[n,c,s,j],
//   din[...,0..1] = x[n,c,2s..2s+1], din[...,2] = d[n,c,s].
// GEMM view: out[o, col] = sum_k A[o,k] B[k,col], col=(n,s), K=96.
// K reorder: k = 2c+j for j in {0,1} (x part), k = 64+c for j=2 (d part).
//
// R3 theory: R2's staged-LDS kernel was latency-bound (Mfma 1.2%, VALU 15%,
// HBM 20%, occupancy 24% -- all idle). B/A staging through LDS cost two
// barriers, 3.5M bank-conflict cycles (ushort scatter), and 46.6KB LDS
// (3 blocks/CU = 9 waves). Fix: gather MFMA fragments directly from global.
// Each B element is consumed by exactly ONE lane exactly once (the 6 s-slots
// tile x[n,:,:]), so HBM traffic is unchanged; per ct a lane needs only
// 2 base addresses + immediate offsets (8x float2 of x, 8x dword of d).
// LDS shrinks to obuf only (25.6KB -> 6 blocks/CU) and each wave carries
// ~64 independent outstanding loads.
// Fragment mappings per verified m89/m91/m97 chain (16x16x32_bf16):
//   A[m=lane&15][k=(lane>>4)*8+j], B[k=(lane>>4)*8+j][n=lane&15],
//   C/D: col=lane&15, row=(lane>>4)*4+reg.

#define ND 32
#define NPAIR 6
#define SPB 32                  // samples per block
#define BT 192                  // 3 waves
#define OSTR 200                // obuf dword stride per sample (192 + 8 pad)

typedef __attribute__((ext_vector_type(8))) short bf16x8;
typedef __attribute__((ext_vector_type(4))) float f32x4;

union BU { unsigned u[4]; bf16x8 v; };

// pack two fp32 -> two bf16 (truncate): low16 = bf16(lo), high16 = bf16(hi)
__device__ __forceinline__ unsigned pack2(float lo, float hi) {
    return __builtin_amdgcn_perm(__float_as_uint(hi), __float_as_uint(lo), 0x07060302u);
}

__global__ __launch_bounds__(BT) void dijet_mfma(
    const float* __restrict__ x,    // [N, 32, 12]
    const float* __restrict__ d,    // [N, 32, 6]
    const float* __restrict__ W,    // [32, 32, 3]
    const float* __restrict__ bias, // [32]
    float* __restrict__ out,        // [N, 32, 6]
    int N)
{
    __shared__ __align__(16) float obuf[SPB * OSTR];   // 25600 B -> 6 blocks/CU

    const int t    = threadIdx.x;
    const int n0   = blockIdx.x * SPB;
    const bool full = (n0 + SPB <= N);

    const int w     = t >> 6;
    const int l     = t & 63;
    const int row16 = l & 15;
    const int quad  = l >> 4;
    const int ct0   = w * 4;       // wave owns col-tiles ct0..ct0+3

    // ---- A fragments: direct gather from W (12 KB, L1/L2-resident) ----
    // Af[ot][ks] reg j' holds k = ks*32 + quad*8 + j'.
    // ks=0,1: c = 16*ks + quad*4 + (j'>>1), j = j'&1 -> W[o*96 + c*3 + j]
    // ks=2:   c = quad*8 + j', j = 2        -> W[o*96 + c*3 + 2]
    bf16x8 Af[2][3];
#pragma unroll
    for (int ot = 0; ot < 2; ++ot) {
        const float* wb = W + (ot * 16 + row16) * 96;
        const float* wq = wb + quad * 12;           // ks=0,1 base (c = quad*4)
#pragma unroll
        for (int ks = 0; ks < 2; ++ks) {
            BU b;
#pragma unroll
            for (int cc = 0; cc < 4; ++cc) {
                const float* p = wq + (16 * ks + cc) * 3;
                b.u[cc] = pack2(p[0], p[1]);
            }
            Af[ot][ks] = b.v;
        }
        const float* wq2 = wb + quad * 24 + 2;      // ks=2 base (c = quad*8)
        BU b2;
#pragma unroll
        for (int m = 0; m < 4; ++m)
            b2.u[m] = pack2(wq2[(2 * m) * 3], wq2[(2 * m + 1) * 3]);
        Af[ot][2] = b2.v;
    }

    // accumulators init with bias: reg r of (ct, ot) holds o = ot*16 + quad*4 + r
    float4 bv0 = *(const float4*)(bias + quad * 4);
    float4 bv1 = *(const float4*)(bias + 16 + quad * 4);
    f32x4 acc[4][2];
#pragma unroll
    for (int ct = 0; ct < 4; ++ct) {
        acc[ct][0] = (f32x4){bv0.x, bv0.y, bv0.z, bv0.w};
        acc[ct][1] = (f32x4){bv1.x, bv1.y, bv1.z, bv1.w};
    }

    // ---- B fragments: direct gather from x/d, convert, MFMA ----
#pragma unroll
    for (int ct = 0; ct < 4; ++ct) {
        const int col = (ct0 + ct) * 16 + row16;
        const int ls  = col / 6;
        const int s   = col - ls * 6;
        const bool ok = full || (n0 + ls < N);

        // x[n, c, e] at n*384 + c*12 + e ; B0/B1 need c = quad*4+cc (+16)
        const float* xp = x + (size_t)(n0 + ls) * 384 + quad * 48 + 2 * s;
        // d[n, c, s] at n*192 + c*6 + s ; B2 needs c = quad*8 + j'
        const float* dp = d + (size_t)(n0 + ls) * 192 + quad * 48 + s;

        float2 v0[4], v1[4];
        float  vd[8];
#pragma unroll
        for (int cc = 0; cc < 4; ++cc) {
            v0[cc] = ok ? *(const float2*)(xp + cc * 12)       : make_float2(0.f, 0.f);
            v1[cc] = ok ? *(const float2*)(xp + 192 + cc * 12) : make_float2(0.f, 0.f);
        }
#pragma unroll
        for (int j = 0; j < 8; ++j)
            vd[j] = ok ? dp[j * 6] : 0.f;

        BU b0, b1, b2;
#pragma unroll
        for (int cc = 0; cc < 4; ++cc) {
            b0.u[cc] = pack2(v0[cc].x, v0[cc].y);
            b1.u[cc] = pack2(v1[cc].x, v1[cc].y);
        }
#pragma unroll
        for (int m = 0; m < 4; ++m)
            b2.u[m] = pack2(vd[2 * m], vd[2 * m + 1]);

        acc[ct][0] = __builtin_amdgcn_mfma_f32_16x16x32_bf16(Af[0][0], b0.v, acc[ct][0], 0, 0, 0);
        acc[ct][0] = __builtin_amdgcn_mfma_f32_16x16x32_bf16(Af[0][1], b1.v, acc[ct][0], 0, 0, 0);
        acc[ct][0] = __builtin_amdgcn_mfma_f32_16x16x32_bf16(Af[0][2], b2.v, acc[ct][0], 0, 0, 0);
        acc[ct][1] = __builtin_amdgcn_mfma_f32_16x16x32_bf16(Af[1][0], b0.v, acc[ct][1], 0, 0, 0);
        acc[ct][1] = __builtin_amdgcn_mfma_f32_16x16x32_bf16(Af[1][1], b1.v, acc[ct][1], 0, 0, 0);
        acc[ct][1] = __builtin_amdgcn_mfma_f32_16x16x32_bf16(Af[1][2], b2.v, acc[ct][1], 0, 0, 0);
    }

    // ---- epilogue: C/D -> padded LDS out-layout ----
#pragma unroll
    for (int ct = 0; ct < 4; ++ct) {
        const int col = (ct0 + ct) * 16 + row16;
        const int ls  = col / 6;
        const int s   = col - ls * 6;
        float* ob = obuf + ls * OSTR + s;
#pragma unroll
        for (int ot = 0; ot < 2; ++ot) {
            const int o0 = ot * 16 + quad * 4;
            ob[(o0 + 0) * NPAIR] = acc[ct][ot].x;
            ob[(o0 + 1) * NPAIR] = acc[ct][ot].y;
            ob[(o0 + 2) * NPAIR] = acc[ct][ot].z;
            ob[(o0 + 3) * NPAIR] = acc[ct][ot].w;
        }
    }

    __syncthreads();

    // ---- coalesced float4 writeback (proven in R2: exact-ideal WRITE_SIZE) ----
    float* og = out + (size_t)n0 * (ND * NPAIR);
#pragma unroll
    for (int k = 0; k < 8; ++k) {
        const int F  = 4 * (t + k * BT);     // [0, 6144)
        const int ns = F / 192;
        const int wi = F % 192;
        if (full || n0 + ns < N) {
            float4 v = *(const float4*)(obuf + ns * OSTR + wi);
            *(float4*)(og + ns * 192 + wi) = v;
        }
    }
}

extern "C" void kernel_launch(void* const* d_in, const int* in_sizes, int n_in,
                              void* d_out, int out_size, void* d_ws, size_t ws_size,
                              hipStream_t stream) {
    const float* x = (const float*)d_in[0];
    const float* d = (const float*)d_in[1];
    const float* W = (const float*)d_in[2];
    const float* b = (const float*)d_in[3];
    float* out = (float*)d_out;

    int N = in_sizes[0] / (ND * 2 * NPAIR);
    int blocks = (N + SPB - 1) / SPB;

    dijet_mfma<<<blocks, BT, 0, stream>>>(x, d, W, b, out, N);
}